// Round 2
// baseline (592.406 us; speedup 1.0000x reference)
//
#include <hip/hip_runtime.h>
#include <hip/hip_bf16.h>
#include <math.h>

using bf16 = __hip_bfloat16;
typedef __bf16 bf16x8 __attribute__((ext_vector_type(8)));
typedef float f32x4 __attribute__((ext_vector_type(4)));

static constexpr int B_ = 2, T_ = 2048, D_ = 1024, H_ = 16, HD_ = 64, FH_ = 2752;
static constexpr int BT = B_ * T_;  // 4096

struct __align__(8)  bh4 { bf16 h[4]; };
struct __align__(16) bh8 { bf16 h[8]; };

#define DEV static __device__ __forceinline__

DEV float b2f(bf16 v) { return __bfloat162float(v); }
DEV bf16  f2b(float v) { return __float2bfloat16(v); }
DEV float sigmoidf_(float x) { return 1.0f / (1.0f + __expf(-x)); }

DEV void load4f(const bf16* p, float* v) {
    bh4 t = *reinterpret_cast<const bh4*>(p);
#pragma unroll
    for (int i = 0; i < 4; ++i) v[i] = b2f(t.h[i]);
}
DEV void load4f(const float* p, float* v) {
    float4 t = *reinterpret_cast<const float4*>(p);
    v[0] = t.x; v[1] = t.y; v[2] = t.z; v[3] = t.w;
}
DEV void store4(float* p, const float* v) {
    float4 t; t.x = v[0]; t.y = v[1]; t.z = v[2]; t.w = v[3];
    *reinterpret_cast<float4*>(p) = t;
}
DEV void store4(bf16* p, const float* v) {
    bh4 t;
#pragma unroll
    for (int i = 0; i < 4; ++i) t.h[i] = f2b(v[i]);
    *reinterpret_cast<bh4*>(p) = t;
}
DEV float waveReduceSum(float v) {
#pragma unroll
    for (int m = 32; m; m >>= 1) v += __shfl_xor(v, m);
    return v;
}

// ---------------- RoPE tables: cos/sin[t][j], j=0..31 ----------------
__global__ __launch_bounds__(256) void k_rope_tables(float* __restrict__ cost, float* __restrict__ sint) {
    int idx = blockIdx.x * 256 + threadIdx.x;
    if (idx >= T_ * 32) return;
    int t = idx >> 5, j = idx & 31;
    float inv = powf(10000.0f, -(float)j * (1.0f / 32.0f));
    float f = (float)t * inv;
    cost[idx] = cosf(f);
    sint[idx] = sinf(f);
}

// ---------------- RMSNorm over D=1024 (f32 in, f32 weight, bf16 out), one block per row ----------------
__global__ __launch_bounds__(256) void k_rmsnorm(const float* __restrict__ x, const float* __restrict__ w,
                                                 bf16* __restrict__ out) {
    int row = blockIdx.x, tid = threadIdx.x;
    const float* xr = x + (size_t)row * D_;
    int base = tid * 4;
    float v[4];
    load4f(xr + base, v);
    float ss = v[0]*v[0] + v[1]*v[1] + v[2]*v[2] + v[3]*v[3];
    ss = waveReduceSum(ss);
    __shared__ float red[4];
    if ((tid & 63) == 0) red[tid >> 6] = ss;
    __syncthreads();
    ss = red[0] + red[1] + red[2] + red[3];
    float r = rsqrtf(ss * (1.0f / D_) + 1e-6f);
    float wv[4];
    load4f(w + base, wv);
    bh4 o;
#pragma unroll
    for (int i = 0; i < 4; ++i) o.h[i] = f2b(v[i] * r * wv[i]);
    *reinterpret_cast<bh4*>(out + (size_t)row * D_ + base) = o;
}

// ---------------- GEMM: C[M,N] = A[M,K](bf16) @ W[N,K]^T(f32->bf16) , bf16 out, f32 acc ----------------
// 128x128 tile, BK=32, 4 waves (2x2), each wave 64x64 via 4x4 mfma_f32_16x16x32_bf16 frags.
__global__ __launch_bounds__(256) void k_gemm_bt(const bf16* __restrict__ A, const float* __restrict__ W,
                                                 bf16* __restrict__ C, int M, int N, int K) {
    constexpr int LDT = 40;  // padded row (elems) to break LDS bank conflicts
    __shared__ bf16 sA[128 * LDT];
    __shared__ bf16 sB[128 * LDT];
    int m0 = blockIdx.x * 128, n0 = blockIdx.y * 128;
    int tid = threadIdx.x, lane = tid & 63, wid = tid >> 6;
    int wr = wid >> 1, wc = wid & 1;
    int l16 = lane & 15, lg = lane >> 4;
    int arow = tid >> 2, acol = (tid & 3) * 8;   // staging: thread covers 8 K-elems per half-tile row

    f32x4 acc[4][4] = {};

    for (int k0 = 0; k0 < K; k0 += 32) {
#pragma unroll
        for (int c = 0; c < 2; ++c) {
            int row = c * 64 + arow;
            *reinterpret_cast<bh8*>(&sA[row * LDT + acol]) =
                *reinterpret_cast<const bh8*>(&A[(size_t)(m0 + row) * K + k0 + acol]);
            int nrow = n0 + row;
            if (nrow > N - 1) nrow = N - 1;  // clamp (garbage rows masked at store)
            const float* wp = &W[(size_t)nrow * K + k0 + acol];
            float4 fa = reinterpret_cast<const float4*>(wp)[0];
            float4 fb = reinterpret_cast<const float4*>(wp)[1];
            bh8 wb;
            wb.h[0] = f2b(fa.x); wb.h[1] = f2b(fa.y); wb.h[2] = f2b(fa.z); wb.h[3] = f2b(fa.w);
            wb.h[4] = f2b(fb.x); wb.h[5] = f2b(fb.y); wb.h[6] = f2b(fb.z); wb.h[7] = f2b(fb.w);
            *reinterpret_cast<bh8*>(&sB[row * LDT + acol]) = wb;
        }
        __syncthreads();
        bf16x8 af[4], bfr[4];
#pragma unroll
        for (int m = 0; m < 4; ++m)
            af[m] = *reinterpret_cast<const bf16x8*>(&sA[(wr * 64 + m * 16 + l16) * LDT + lg * 8]);
#pragma unroll
        for (int n = 0; n < 4; ++n)
            bfr[n] = *reinterpret_cast<const bf16x8*>(&sB[(wc * 64 + n * 16 + l16) * LDT + lg * 8]);
#pragma unroll
        for (int m = 0; m < 4; ++m)
#pragma unroll
            for (int n = 0; n < 4; ++n)
                acc[m][n] = __builtin_amdgcn_mfma_f32_16x16x32_bf16(af[m], bfr[n], acc[m][n], 0, 0, 0);
        __syncthreads();
    }
    // epilogue: C/D layout col = lane&15, row = (lane>>4)*4 + r
    int rbase = m0 + wr * 64, cbase = n0 + wc * 64;
#pragma unroll
    for (int m = 0; m < 4; ++m) {
#pragma unroll
        for (int n = 0; n < 4; ++n) {
            int col = cbase + n * 16 + l16;
            if (col < N) {
#pragma unroll
                for (int r = 0; r < 4; ++r) {
                    int row = rbase + m * 16 + lg * 4 + r;
                    C[(size_t)row * N + col] = f2b(acc[m][n][r]);
                }
            }
        }
    }
}

// ---------------- per-head RMSNorm + RoPE, (B*T, D) bf16 -> (B,H,T,HD) bf16 ----------------
__global__ __launch_bounds__(256) void k_qk_norm_rope(const bf16* __restrict__ qin, const float* __restrict__ wn,
                                                      const float* __restrict__ cost, const float* __restrict__ sint,
                                                      bf16* __restrict__ qout, float scale) {
    int tid = threadIdx.x;
    int g = blockIdx.x * 4 + (tid >> 6);     // (b,t,h) group, one wave each
    int d = tid & 63;
    int h = g % H_, t = (g / H_) % T_, b = g / (H_ * T_);
    float v = b2f(qin[(size_t)(b * T_ + t) * D_ + h * HD_ + d]);
    float ss = waveReduceSum(v * v);
    float r = rsqrtf(ss * (1.0f / HD_) + 1e-6f);
    float xn = v * r * wn[d];
    float p = __shfl_xor(xn, 32);
    float c = cost[t * 32 + (d & 31)], s = sint[t * 32 + (d & 31)];
    float o = (d < 32) ? (xn * c - p * s) : (xn * c + p * s);
    qout[((size_t)(b * H_ + h) * T_ + t) * HD_ + d] = f2b(o * scale);
}

// ---------------- V: (B*T, D) -> (B,H,HD,T) transposed for PV fragments ----------------
__global__ __launch_bounds__(256) void k_v_transpose(const bf16* __restrict__ vin, bf16* __restrict__ vt) {
    __shared__ bf16 tile[64][72];
    int tid = threadIdx.x;
    int bh = blockIdx.y;            // b*H+h
    int t0 = blockIdx.x * 64;
    int b = bh >> 4, h = bh & 15;
#pragma unroll
    for (int i = 0; i < 16; ++i) {
        int lin = i * 256 + tid;
        int tl = lin >> 6, d = lin & 63;
        tile[tl][d] = vin[(size_t)(b * T_ + t0 + tl) * D_ + h * HD_ + d];
    }
    __syncthreads();
#pragma unroll
    for (int i = 0; i < 16; ++i) {
        int lin = i * 256 + tid;
        int d = lin >> 6, tl = lin & 63;
        vt[((size_t)bh * HD_ + d) * T_ + t0 + tl] = tile[tl][d];
    }
}

// ---------------- Flash attention (causal). Q,K: (B,H,T,HD) bf16 (Q pre-scaled); Vt: (B,H,HD,T). ----------------
// 4 waves x 16 q-rows per block (q-tile 64), KV tile 64, online softmax.
__global__ __launch_bounds__(256) void k_flash(const bf16* __restrict__ Q, const bf16* __restrict__ Kk,
                                               const bf16* __restrict__ Vt, bf16* __restrict__ Out) {
    constexpr int PLD = 80;  // padded (16B-aligned) P row
    __shared__ bf16 P[4][16][PLD];
    int tid = threadIdx.x, lane = tid & 63, w = tid >> 6;
    int l16 = lane & 15, lg = lane >> 4;
    int qt0 = blockIdx.x * 64;
    int bh = blockIdx.y;
    int b = bh >> 4, h = bh & 15;
    const bf16* qb = Q + (size_t)bh * T_ * HD_;
    const bf16* kb = Kk + (size_t)bh * T_ * HD_;
    const bf16* vb = Vt + (size_t)bh * HD_ * T_;

    bf16x8 qf[2];
    int qrow = qt0 + w * 16 + l16;
#pragma unroll
    for (int kk = 0; kk < 2; ++kk)
        qf[kk] = *reinterpret_cast<const bf16x8*>(&qb[(size_t)qrow * HD_ + kk * 32 + lg * 8]);

    f32x4 acc_o[4] = {};
    float m_r[4], l_r[4];
#pragma unroll
    for (int r = 0; r < 4; ++r) { m_r[r] = -INFINITY; l_r[r] = 0.0f; }

    for (int kv0 = 0; kv0 <= qt0; kv0 += 64) {
        f32x4 s[4] = {};
#pragma unroll
        for (int kk = 0; kk < 2; ++kk) {
#pragma unroll
            for (int n = 0; n < 4; ++n) {
                bf16x8 kf = *reinterpret_cast<const bf16x8*>(
                    &kb[(size_t)(kv0 + n * 16 + l16) * HD_ + kk * 32 + lg * 8]);
                s[n] = __builtin_amdgcn_mfma_f32_16x16x32_bf16(qf[kk], kf, s[n], 0, 0, 0);
            }
        }
        float pf[4][4];
#pragma unroll
        for (int r = 0; r < 4; ++r) {
            int qg = qt0 + w * 16 + lg * 4 + r;
            float mx = -INFINITY;
#pragma unroll
            for (int n = 0; n < 4; ++n) {
                int kvg = kv0 + n * 16 + l16;
                float sv = (kvg <= qg) ? s[n][r] : -INFINITY;
                pf[n][r] = sv;
                mx = fmaxf(mx, sv);
            }
            mx = fmaxf(mx, __shfl_xor(mx, 1));
            mx = fmaxf(mx, __shfl_xor(mx, 2));
            mx = fmaxf(mx, __shfl_xor(mx, 4));
            mx = fmaxf(mx, __shfl_xor(mx, 8));
            float mnew = fmaxf(m_r[r], mx);
            float corr = __expf(m_r[r] - mnew);   // exp(-inf)=0 on first tile
            m_r[r] = mnew;
            float ps = 0.0f;
#pragma unroll
            for (int n = 0; n < 4; ++n) {
                float p = (pf[n][r] == -INFINITY) ? 0.0f : __expf(pf[n][r] - mnew);
                pf[n][r] = p;
                ps += p;
            }
            l_r[r] = l_r[r] * corr + ps;
#pragma unroll
            for (int n = 0; n < 4; ++n) acc_o[n][r] *= corr;
        }
        __syncthreads();   // prior PV reads complete before overwrite
#pragma unroll
        for (int r = 0; r < 4; ++r)
#pragma unroll
            for (int n = 0; n < 4; ++n)
                P[w][lg * 4 + r][n * 16 + l16] = f2b(pf[n][r]);
        __syncthreads();   // P visible before fragment reads
#pragma unroll
        for (int kk = 0; kk < 2; ++kk) {
            bf16x8 pa = *reinterpret_cast<const bf16x8*>(&P[w][l16][kk * 32 + lg * 8]);
#pragma unroll
            for (int n = 0; n < 4; ++n) {
                bf16x8 vf = *reinterpret_cast<const bf16x8*>(
                    &vb[(size_t)(n * 16 + l16) * T_ + kv0 + kk * 32 + lg * 8]);
                acc_o[n] = __builtin_amdgcn_mfma_f32_16x16x32_bf16(pa, vf, acc_o[n], 0, 0, 0);
            }
        }
    }
#pragma unroll
    for (int r = 0; r < 4; ++r) {
        float tot = l_r[r];
        tot += __shfl_xor(tot, 1);
        tot += __shfl_xor(tot, 2);
        tot += __shfl_xor(tot, 4);
        tot += __shfl_xor(tot, 8);
        float inv = 1.0f / tot;
        int qg = qt0 + w * 16 + lg * 4 + r;
#pragma unroll
        for (int n = 0; n < 4; ++n)
            Out[(size_t)(b * T_ + qg) * D_ + h * HD_ + n * 16 + l16] = f2b(acc_o[n][r] * inv);
    }
}

// ---------------- delta_res: one block per row, 5 fused row-reductions ----------------
// x: TIN (f32), h: bf16 (GEMM out), vectors f32, out: TOUT
template <typename TIN, typename TOUT>
__global__ __launch_bounds__(256) void k_delta_res(const TIN* __restrict__ x, const bf16* __restrict__ h,
                                                   const float* __restrict__ gn_w, const float* __restrict__ g_w,
                                                   const float* __restrict__ g_b, const float* __restrict__ wv_w,
                                                   TOUT* __restrict__ out) {
    int row = blockIdx.x, tid = threadIdx.x;
    int base = tid * 4;
    float xv[4], hv[4], gnv[4], gwv[4], wvv[4];
    load4f(x + (size_t)row * D_ + base, xv);
    load4f(h + (size_t)row * D_ + base, hv);
    load4f(gn_w + base, gnv);
    load4f(g_w + base, gwv);
    load4f(wv_w + base, wvv);
    float s_h2 = 0, s_x2 = 0, s_xg = 0, s_xv = 0, s_hx = 0;
#pragma unroll
    for (int i = 0; i < 4; ++i) {
        s_h2 += hv[i] * hv[i];
        s_x2 += xv[i] * xv[i];
        s_xg += xv[i] * gnv[i] * gwv[i];
        s_xv += xv[i] * wvv[i];
        s_hx += hv[i] * xv[i];
    }
    s_h2 = waveReduceSum(s_h2); s_x2 = waveReduceSum(s_x2); s_xg = waveReduceSum(s_xg);
    s_xv = waveReduceSum(s_xv); s_hx = waveReduceSum(s_hx);
    __shared__ float red[4][5];
    int wid = tid >> 6;
    if ((tid & 63) == 0) {
        red[wid][0] = s_h2; red[wid][1] = s_x2; red[wid][2] = s_xg;
        red[wid][3] = s_xv; red[wid][4] = s_hx;
    }
    __syncthreads();
    s_h2 = red[0][0] + red[1][0] + red[2][0] + red[3][0];
    s_x2 = red[0][1] + red[1][1] + red[2][1] + red[3][1];
    s_xg = red[0][2] + red[1][2] + red[2][2] + red[3][2];
    s_xv = red[0][3] + red[1][3] + red[2][3] + red[3][3];
    s_hx = red[0][4] + red[1][4] + red[2][4] + red[3][4];

    float r = rsqrtf(s_x2 * (1.0f / D_) + 1e-6f);
    float logit = r * s_xg + g_b[0];
    float beta = 2.0f * sigmoidf_(logit);
    float vsig = sigmoidf_(s_xv);
    float nrm = sqrtf(s_h2);
    float ks = (1.0f / 32.0f) / fmaxf(nrm, 1e-6f);   // 1/sqrt(D)=1/32
    float coef = beta * (vsig - ks * s_hx) * ks;
    float o[4];
#pragma unroll
    for (int i = 0; i < 4; ++i) o[i] = xv[i] + coef * hv[i];
    store4(out + (size_t)row * D_ + base, o);
}

// ---------------- gate: g = silu(h1) * h3 (in-place over h1 ok) ----------------
__global__ __launch_bounds__(256) void k_gate(const bf16* __restrict__ h1, const bf16* __restrict__ h3,
                                              bf16* __restrict__ g, int n8) {
    int i = blockIdx.x * 256 + threadIdx.x;
    if (i >= n8) return;
    bh8 a = *reinterpret_cast<const bh8*>(h1 + (size_t)i * 8);
    bh8 b = *reinterpret_cast<const bh8*>(h3 + (size_t)i * 8);
    bh8 o;
#pragma unroll
    for (int j = 0; j < 8; ++j) {
        float av = b2f(a.h[j]), bv = b2f(b.h[j]);
        o.h[j] = f2b(av * sigmoidf_(av) * bv);
    }
    *reinterpret_cast<bh8*>(g + (size_t)i * 8) = o;
}

extern "C" void kernel_launch(void* const* d_in, const int* in_sizes, int n_in,
                              void* d_out, int out_size, void* d_ws, size_t ws_size,
                              hipStream_t stream) {
    const float* x       = (const float*)d_in[0];
    const float* wq      = (const float*)d_in[1];
    const float* wk      = (const float*)d_in[2];
    const float* wv      = (const float*)d_in[3];
    const float* wo      = (const float*)d_in[4];
    const float* qn_w    = (const float*)d_in[5];
    const float* kn_w    = (const float*)d_in[6];
    const float* attn_nw = (const float*)d_in[7];
    const float* g1_nw   = (const float*)d_in[8];
    const float* g1_w    = (const float*)d_in[9];
    const float* g1_b    = (const float*)d_in[10];
    const float* wv1     = (const float*)d_in[11];
    const float* mlp_nw  = (const float*)d_in[12];
    const float* w1      = (const float*)d_in[13];
    const float* w2      = (const float*)d_in[14];
    const float* w3      = (const float*)d_in[15];
    const float* g2_nw   = (const float*)d_in[16];
    const float* g2_w    = (const float*)d_in[17];
    const float* g2_b    = (const float*)d_in[18];
    const float* wv2     = (const float*)d_in[19];
    float* out = (float*)d_out;

    char* ws = (char*)d_ws;
    const size_t KB = 1024;
    const size_t MB = 1024 * 1024;
    // layout (72.5 MB total, with reuse):
    float* cost = (float*)(ws);                        // 256 KB
    float* sint = (float*)(ws + 256 * KB);             // 256 KB
    bf16* xc    = (bf16*)(ws + 512 * KB);              // 8MB: xc, then xm, then h_mlp
    bf16* qb    = (bf16*)(ws + 512 * KB + 8  * MB);    // 8MB: q, then attn_out; later part of h3
    bf16* kbuf  = (bf16*)(ws + 512 * KB + 16 * MB);    // 8MB: k, then h_attn; later part of h3
    bf16* vbuf  = (bf16*)(ws + 512 * KB + 24 * MB);    // 8MB: v; later part of h3
    bf16* Qr    = (bf16*)(ws + 512 * KB + 32 * MB);    // 8MB; later part of h1
    bf16* Kr    = (bf16*)(ws + 512 * KB + 40 * MB);    // 8MB; later part of h1
    bf16* Vt    = (bf16*)(ws + 512 * KB + 48 * MB);    // 8MB; later part of h1
    float* x1   = (float*)(ws + 512 * KB + 56 * MB);   // 16MB f32
    bf16* h1    = Qr;                                  // 22.5MB (reuses Qr/Kr/Vt region: 24MB)
    bf16* h3    = qb;                                  // 22.5MB (reuses qb/kbuf/vbuf region: 24MB)
    bf16* hmlp  = xc;                                  // 8MB (reuses xc/xm after last use)

    k_rope_tables<<<dim3((T_ * 32) / 256), dim3(256), 0, stream>>>(cost, sint);

    // xc = rmsnorm(x, attn_norm_w)
    k_rmsnorm<<<dim3(BT), dim3(256), 0, stream>>>(x, attn_nw, xc);

    dim3 gqkv(BT / 128, D_ / 128);
    k_gemm_bt<<<gqkv, dim3(256), 0, stream>>>(xc, wq, qb,   BT, D_, D_);
    k_gemm_bt<<<gqkv, dim3(256), 0, stream>>>(xc, wk, kbuf, BT, D_, D_);
    k_gemm_bt<<<gqkv, dim3(256), 0, stream>>>(xc, wv, vbuf, BT, D_, D_);

    // per-head norm + rope (+1/sqrt(HD) folded into Q), layout to (B,H,T,HD)
    k_qk_norm_rope<<<dim3(BT * H_ / 4), dim3(256), 0, stream>>>(qb,   qn_w, cost, sint, Qr, 0.125f);
    k_qk_norm_rope<<<dim3(BT * H_ / 4), dim3(256), 0, stream>>>(kbuf, kn_w, cost, sint, Kr, 1.0f);
    k_v_transpose<<<dim3(T_ / 64, B_ * H_), dim3(256), 0, stream>>>(vbuf, Vt);

    // flash attention -> attn_out (reuse qb)
    k_flash<<<dim3(T_ / 64, B_ * H_), dim3(256), 0, stream>>>(Qr, Kr, Vt, qb);

    // h_attn = attn_out @ wo^T  (reuse kbuf)
    k_gemm_bt<<<gqkv, dim3(256), 0, stream>>>(qb, wo, kbuf, BT, D_, D_);

    // x1 = delta_res(x, h_attn, g1...)  (f32)
    k_delta_res<float, float><<<dim3(BT), dim3(256), 0, stream>>>(x, kbuf, g1_nw, g1_w, g1_b, wv1, x1);

    // xm = rmsnorm(x1, mlp_norm_w) -> xc region
    k_rmsnorm<<<dim3(BT), dim3(256), 0, stream>>>(x1, mlp_nw, xc);

    dim3 gffn(BT / 128, (FH_ + 127) / 128);
    k_gemm_bt<<<gffn, dim3(256), 0, stream>>>(xc, w1, h1, BT, FH_, D_);
    k_gemm_bt<<<gffn, dim3(256), 0, stream>>>(xc, w3, h3, BT, FH_, D_);

    // g = silu(h1)*h3, in place over h1
    int n8 = BT * FH_ / 8;
    k_gate<<<dim3((n8 + 255) / 256), dim3(256), 0, stream>>>(h1, h3, h1, n8);

    // h_mlp = g @ w2^T  -> hmlp (reuses xc region; xm dead after w1/w3 GEMMs)
    k_gemm_bt<<<gqkv, dim3(256), 0, stream>>>(h1, w2, hmlp, BT, D_, FH_);

    // out = delta_res(x1, h_mlp, g2...) (f32 out)
    k_delta_res<float, float><<<dim3(BT), dim3(256), 0, stream>>>(x1, hmlp, g2_nw, g2_w, g2_b, wv2, out);
}